// Round 3
// baseline (550.933 us; speedup 1.0000x reference)
//
#include <hip/hip_runtime.h>
#include <hip/hip_bf16.h>

typedef unsigned short u16;
typedef short s16x8 __attribute__((ext_vector_type(8)));
typedef unsigned int u32x2 __attribute__((ext_vector_type(2)));
typedef float f32x4 __attribute__((ext_vector_type(4)));

#define F_DIM 2048
#define A_DIM 1024
#define H_DIM 1024
#define BATCH 128
#define LLEN  196
#define MROWS (BATCH * LLEN)   // 25088
#define MTILES (MROWS / 256)   // 98

__device__ __forceinline__ u16 f2b(float x) {
  union { float f; unsigned int u; } c; c.f = x;
  unsigned int r = (c.u + 0x7fffu + ((c.u >> 16) & 1u)) >> 16;  // RNE
  return (u16)r;
}

__device__ __forceinline__ unsigned int f2b_pk(float a, float b) {
  unsigned int r;
  asm volatile("v_cvt_pk_bf16_f32 %0, %1, %2" : "=v"(r) : "v"(a), "v"(b));
  return r;
}

__device__ __forceinline__ void gload_lds16(const void* g, void* l) {
  __builtin_amdgcn_global_load_lds((const __attribute__((address_space(1))) void*)g,
                                   (__attribute__((address_space(3))) void*)l, 16, 0, 0);
}

// ---------------------------------------------------------------------------
// K0: W_enc (2048x1024 fp32, k-major) -> WT (1024x2048 bf16, a-major)
__global__ void wenc_cvt_kernel(const float* __restrict__ W, u16* __restrict__ WT) {
  __shared__ float tile[32][33];
  int kb = blockIdx.x * 32, ab = blockIdx.y * 32;
  int t = threadIdx.x;
  int r = t >> 3, c = (t & 7) * 4;
  float4 v = *(const float4*)&W[(size_t)(kb + r) * A_DIM + ab + c];
  tile[r][c] = v.x; tile[r][c + 1] = v.y; tile[r][c + 2] = v.z; tile[r][c + 3] = v.w;
  __syncthreads();
  ushort4 o;
  o.x = f2b(tile[c + 0][r]);
  o.y = f2b(tile[c + 1][r]);
  o.z = f2b(tile[c + 2][r]);
  o.w = f2b(tile[c + 3][r]);
  *(ushort4*)&WT[(size_t)(ab + r) * F_DIM + kb + c] = o;
}

// ---------------------------------------------------------------------------
// K1: attn2p[b][a] = hidden[b]·W_hid[:,a] + b_hid[a] + b_enc[a].
// Non-atomic: block owns (a-chunk of 256, b-group of 4), full K=1024 in-block.
// Grid (4, 32) = 128 blocks; no memset, no atomics.
__global__ __launch_bounds__(256) void attn2_kernel(
    const float* __restrict__ hidden, const float* __restrict__ W_hid,
    const float* __restrict__ b_hid, const float* __restrict__ b_enc,
    float* __restrict__ attn2p) {
  __shared__ float hl[4][H_DIM];
  int t = threadIdx.x;
  int a  = blockIdx.x * 256 + t;
  int b0 = blockIdx.y * 4;
  float* hf = &hl[0][0];
  #pragma unroll
  for (int j = 0; j < 4; ++j) {
    int s = j * 256 + t;   // float4 slot over 4 contiguous rows
    *(float4*)&hf[s * 4] = *(const float4*)&hidden[(size_t)b0 * H_DIM + s * 4];
  }
  __syncthreads();
  float acc[4] = {0.f, 0.f, 0.f, 0.f};
  #pragma unroll 4
  for (int k = 0; k < H_DIM; ++k) {
    float w = W_hid[(size_t)k * A_DIM + a];
    #pragma unroll
    for (int j = 0; j < 4; ++j) acc[j] = fmaf(hl[j][k], w, acc[j]);
  }
  float bias = b_hid[a] + b_enc[a];
  #pragma unroll
  for (int j = 0; j < 4; ++j)
    attn2p[(size_t)(b0 + j) * A_DIM + a] = acc[j] + bias;
}

// ---------------------------------------------------------------------------
// K2: fused GEMM + score. BM=BN=256, BK=64, 8 waves (2M x 4N), wave 128x64.
// One K-tile per 4-phase group. A is reg-staged with PING-PONG register sets:
// during group T, set W (loaded in group T-1) is cvt_pk'd + ds_written to the
// buffer for tile T+1, while set L is global-loaded with A(T+2). This gives
// every vmem consumer a COUNTED implicit wait with >=3 phases of slack:
//   p0 AWR(W.lo)  -> implicit vmcnt(4)  (W.lo issued T-1 p1)
//   p1 AWR(W.hi)  -> implicit vmcnt(4)  (W.hi issued T-1 p2)
//   p3 explicit vmcnt(8) drains only BGL(T+1) (issued p0)
// No vmcnt(0) anywhere in the main loop (the round-2 schedule had an implicit
// full drain every iteration from the 2-phase ALD->AWR chain).
// T2 XOR swizzle on both tiles (granule ^= row&7): conflict-free b128 reads.
__global__ __launch_bounds__(512, 2) void gemm_score(
    const float* __restrict__ enc, const u16* __restrict__ WT,
    const float* __restrict__ attn2p, const float* __restrict__ W_full,
    float* __restrict__ scores) {
  __shared__ __align__(16) u16 As[2 * 16384];   // 2 bufs x 256 x 64 bf16 = 64 KB
  __shared__ __align__(16) u16 Bs[2 * 16384];   // 64 KB

  int i = blockIdx.x;
  int g = i >> 5, r = i & 31;
  int y = r >> 3, gi = r & 7;
  int mt = g * 8 + gi;
  if (mt >= MTILES) return;              // uniform per-block: no barrier hazard
  int m0 = mt * 256, n0 = y * 256;
  int t = threadIdx.x;
  int lane = t & 63, wave = t >> 6;
  int wr = wave >> 2, wc = wave & 3;     // wave grid 2M x 4N
  int c16 = lane & 15, quad = lane >> 4;

  // A loads: thread covers row t>>2 (of a 128-row half), 4 sites of 4 floats.
  const float* aP = enc + (size_t)(m0 + (t >> 2)) * F_DIM + (t & 3) * 4;
  // A ds_write offsets (b64 each), XOR key (row)&7 on 16B granules.
  int awo[4];
  #pragma unroll
  for (int s = 0; s < 4; ++s)
    awo[s] = (t >> 2) * 64 + ((t & 3) & 1) * 4
           + (((s * 2 + ((t & 3) >> 1)) ^ ((t >> 2) & 7)) * 8);
  // B gload_lds: site s covers rows s*64 + (t>>3); source granule pre-swizzled.
  const u16* bgp = WT + (size_t)(n0 + (t >> 3)) * F_DIM + ((t & 7) ^ ((t >> 3) & 7)) * 8;

  // fragment read offsets (u16 elems)
  const int akey = c16 & 7;
  int gsw[2];
  gsw[0] = ((0 * 4 + quad) ^ akey) * 8;
  gsw[1] = ((1 * 4 + quad) ^ akey) * 8;
  const int aro = (wr * 128 + c16) * 64;
  const int bro = (wc * 64 + c16) * 64;

  f32x4 acc[8][4];
  #pragma unroll
  for (int mi = 0; mi < 8; ++mi)
    #pragma unroll
    for (int ni = 0; ni < 4; ++ni) acc[mi][ni] = (f32x4){0.f, 0.f, 0.f, 0.f};

  s16x8 af[4][2], bf[2][2];
  float4 R0lo[4], R0hi[4], R1lo[4], R1hi[4];   // ping-pong A reg sets

#define ALD(RX, half, kt_) do {                                                 \
    const float* p_ = aP + (size_t)(half) * 128 * F_DIM + (kt_) * 64;           \
    RX[0] = *(const float4*)(p_);                                               \
    RX[1] = *(const float4*)(p_ + 16);                                          \
    RX[2] = *(const float4*)(p_ + 32);                                          \
    RX[3] = *(const float4*)(p_ + 48);                                          \
  } while (0)

#define AWR(RX, cb, half) do {                                                  \
    _Pragma("unroll")                                                           \
    for (int s_ = 0; s_ < 4; ++s_) {                                            \
      u32x2 w_; w_.x = f2b_pk(RX[s_].x, RX[s_].y);                              \
      w_.y = f2b_pk(RX[s_].z, RX[s_].w);                                        \
      *(u32x2*)&As[(cb) * 16384 + (half) * 8192 + awo[s_]] = w_;                \
    }                                                                           \
  } while (0)

#define BGL(cb, kt_) do {                                                       \
    _Pragma("unroll")                                                           \
    for (int s_ = 0; s_ < 4; ++s_)                                              \
      gload_lds16(bgp + (size_t)s_ * 64 * F_DIM + (size_t)(kt_) * 64,           \
                  Bs + (cb) * 16384 + s_ * 4096 + wave * 512);                  \
  } while (0)

#define DSRA(cb, mh)                                                            \
    _Pragma("unroll")                                                           \
    for (int i_ = 0; i_ < 4; ++i_)                                              \
      _Pragma("unroll")                                                         \
      for (int h_ = 0; h_ < 2; ++h_)                                            \
        af[i_][h_] = *(const s16x8*)&As[(cb) * 16384 + aro                      \
                                        + ((mh) * 4 + i_) * 1024 + gsw[h_]];

#define DSRB(cb, nh)                                                            \
    _Pragma("unroll")                                                           \
    for (int j_ = 0; j_ < 2; ++j_)                                              \
      _Pragma("unroll")                                                         \
      for (int h_ = 0; h_ < 2; ++h_)                                            \
        bf[j_][h_] = *(const s16x8*)&Bs[(cb) * 16384 + bro                      \
                                        + ((nh) * 2 + j_) * 1024 + gsw[h_]];

#define PHTAIL(mh, nh) do {                                                     \
    __builtin_amdgcn_s_barrier();                                               \
    asm volatile("s_waitcnt lgkmcnt(0)" ::: "memory");                          \
    __builtin_amdgcn_s_setprio(1);                                              \
    _Pragma("unroll")                                                           \
    for (int i_ = 0; i_ < 4; ++i_)                                              \
      _Pragma("unroll")                                                         \
      for (int j_ = 0; j_ < 2; ++j_)                                            \
        _Pragma("unroll")                                                       \
        for (int h_ = 0; h_ < 2; ++h_)                                          \
          acc[(mh) * 4 + i_][(nh) * 2 + j_] =                                   \
              __builtin_amdgcn_mfma_f32_16x16x32_bf16(                          \
                  af[i_][h_], bf[j_][h_],                                       \
                  acc[(mh) * 4 + i_][(nh) * 2 + j_], 0, 0, 0);                  \
    __builtin_amdgcn_s_setprio(0);                                              \
    __builtin_amdgcn_s_barrier();                                               \
  } while (0)

// Group T: MFMA on buf RB_ (= T&1), stage tile T+1 into WB_, load A(T+2)
// into set L. W-set holds A(T+1), loaded during group T-1.
#define GROUP(T_, RB_, WB_, WLO_, WHI_, LLO_, LHI_) do {                        \
    int kB_ = min((T_) + 1, 31);                                                \
    int kA_ = min((T_) + 2, 31);                                                \
    /* p0 */                                                                    \
    DSRA(RB_, 0); DSRB(RB_, 0);                                                 \
    AWR(WLO_, WB_, 0);                                                          \
    BGL(WB_, kB_);                                                              \
    PHTAIL(0, 0);                                                               \
    /* p1 */                                                                    \
    DSRB(RB_, 1);                                                               \
    AWR(WHI_, WB_, 1);                                                          \
    ALD(LLO_, 0, kA_);                                                          \
    PHTAIL(0, 1);                                                               \
    /* p2 */                                                                    \
    DSRA(RB_, 1); DSRB(RB_, 0);                                                 \
    ALD(LHI_, 1, kA_);                                                          \
    PHTAIL(1, 0);                                                               \
    /* p3 */                                                                    \
    DSRB(RB_, 1);                                                               \
    asm volatile("s_waitcnt vmcnt(8)" ::: "memory");                            \
    PHTAIL(1, 1);                                                               \
  } while (0)

  // ---- prologue: buf0 <- A(0),B(0); R1 <- A(1). Ends with counted vmcnt(8).
  ALD(R0lo, 0, 0);
  ALD(R0hi, 1, 0);
  BGL(0, 0);
  asm volatile("s_waitcnt vmcnt(4)" ::: "memory");   // R0 done; BGL(0) in flight
  AWR(R0lo, 0, 0);
  AWR(R0hi, 0, 1);
  ALD(R1lo, 0, 1);
  ALD(R1hi, 1, 1);
  asm volatile("s_waitcnt vmcnt(8) lgkmcnt(0)" ::: "memory");  // drain BGL(0)
  __builtin_amdgcn_s_barrier();

  // ---- main loop: 32 K-tiles, 4 phases each; static buf/set via unroll-2.
  #pragma unroll 1
  for (int T = 0; T < 32; T += 2) {
    GROUP(T,     0, 1, R1lo, R1hi, R0lo, R0hi);
    GROUP(T + 1, 1, 0, R0lo, R0hi, R1lo, R1hi);
  }
#undef GROUP
#undef PHTAIL
#undef DSRA
#undef DSRB
#undef BGL
#undef AWR
#undef ALD

  // ---- epilogue: relu(attn1 + attn2)·W_full, 16-lane reduce, atomic score.
  int bfirst = m0 / LLEN;                       // block rows span <= 3 batches
  int bnd1 = (bfirst + 1) * LLEN, bnd2 = (bfirst + 2) * LLEN;
  int b1c = min(bfirst + 1, BATCH - 1), b2c = min(bfirst + 2, BATCH - 1);
  float wf[4], a2v0[4], a2v1[4], a2v2[4];
  #pragma unroll
  for (int ni = 0; ni < 4; ++ni) {
    int col = n0 + wc * 64 + ni * 16 + c16;
    wf[ni]   = W_full[col];
    a2v0[ni] = attn2p[(size_t)bfirst * A_DIM + col];
    a2v1[ni] = attn2p[(size_t)b1c * A_DIM + col];
    a2v2[ni] = attn2p[(size_t)b2c * A_DIM + col];
  }
  #pragma unroll
  for (int mi = 0; mi < 8; ++mi) {
    #pragma unroll
    for (int rr = 0; rr < 4; ++rr) {
      int row_g = m0 + wr * 128 + mi * 16 + quad * 4 + rr;
      float p = 0.f;
      #pragma unroll
      for (int ni = 0; ni < 4; ++ni) {
        float a2 = row_g >= bnd1 ? (row_g >= bnd2 ? a2v2[ni] : a2v1[ni]) : a2v0[ni];
        float v = acc[mi][ni][rr] + a2;
        v = fmaxf(v, 0.f);
        p = fmaf(v, wf[ni], p);
      }
      p += __shfl_xor(p, 1);
      p += __shfl_xor(p, 2);
      p += __shfl_xor(p, 4);
      p += __shfl_xor(p, 8);
      if (c16 == 0) atomicAdd(&scores[row_g], p);
    }
  }
}

// ---------------------------------------------------------------------------
// K3: softmax over L=196 per batch row (b_full dropped: softmax-invariant)
__global__ void softmax_kernel(const float* __restrict__ scores, float* __restrict__ alpha) {
  __shared__ float red[8];
  int b = blockIdx.x, t = threadIdx.x;
  float s = (t < LLEN) ? scores[b * LLEN + t] : -3.0e38f;
  float m = s;
  #pragma unroll
  for (int o = 1; o <= 32; o <<= 1) m = fmaxf(m, __shfl_xor(m, o));
  if ((t & 63) == 0) red[t >> 6] = m;
  __syncthreads();
  m = fmaxf(fmaxf(red[0], red[1]), fmaxf(red[2], red[3]));
  float e = (t < LLEN) ? expf(s - m) : 0.f;
  float sum = e;
  #pragma unroll
  for (int o = 1; o <= 32; o <<= 1) sum += __shfl_xor(sum, o);
  __syncthreads();
  if ((t & 63) == 0) red[4 + (t >> 6)] = sum;
  __syncthreads();
  sum = red[4] + red[5] + red[6] + red[7];
  if (t < LLEN) alpha[b * LLEN + t] = e / sum;
}

// ---------------------------------------------------------------------------
// K4: context. Grid (8, 128) = 1024 blocks (16 waves/CU). Block owns
// (b, f-chunk of 256 floats = 64 float4). Threads: f4 = t&63, l-quarter
// t>>6 (49 rows each); LDS 4-way reduce; exact-once enc read, direct store.
__global__ __launch_bounds__(256) void context_kernel(
    const float* __restrict__ enc, const float* __restrict__ alpha,
    float* __restrict__ out) {
  __shared__ float al[LLEN];
  __shared__ float4 part[4][64];
  int b = blockIdx.y, t = threadIdx.x;
  if (t < LLEN) al[t] = alpha[b * LLEN + t];
  __syncthreads();
  int f4 = blockIdx.x * 64 + (t & 63);
  int lq = t >> 6;                 // 0..3, 49 L-rows each
  const float4* e4 = (const float4*)enc
                   + ((size_t)b * LLEN + lq * 49) * (F_DIM / 4) + f4;
  float4 acc = {0.f, 0.f, 0.f, 0.f};
  #pragma unroll 7
  for (int j = 0; j < 49; ++j) {
    float4 v = e4[(size_t)j * (F_DIM / 4)];
    float a = al[lq * 49 + j];
    acc.x = fmaf(v.x, a, acc.x);
    acc.y = fmaf(v.y, a, acc.y);
    acc.z = fmaf(v.z, a, acc.z);
    acc.w = fmaf(v.w, a, acc.w);
  }
  part[lq][t & 63] = acc;
  __syncthreads();
  if (t < 64) {
    float4 p0 = part[0][t], p1 = part[1][t], p2 = part[2][t], p3 = part[3][t];
    float4 s;
    s.x = (p0.x + p1.x) + (p2.x + p3.x);
    s.y = (p0.y + p1.y) + (p2.y + p3.y);
    s.z = (p0.z + p1.z) + (p2.z + p3.z);
    s.w = (p0.w + p1.w) + (p2.w + p3.w);
    *(float4*)(out + (size_t)b * F_DIM + (size_t)(blockIdx.x * 64 + t) * 4) = s;
  }
}

// ---------------------------------------------------------------------------
extern "C" void kernel_launch(void* const* d_in, const int* in_sizes, int n_in,
                              void* d_out, int out_size, void* d_ws, size_t ws_size,
                              hipStream_t stream) {
  const float* enc    = (const float*)d_in[0];
  const float* hidden = (const float*)d_in[1];
  const float* W_enc  = (const float*)d_in[2];
  const float* b_enc  = (const float*)d_in[3];
  const float* W_hid  = (const float*)d_in[4];
  const float* b_hid  = (const float*)d_in[5];
  const float* W_full = (const float*)d_in[6];
  float* out = (float*)d_out;
  float* alpha_out = out + (size_t)BATCH * F_DIM;

  const size_t wt_bytes = (size_t)A_DIM * F_DIM * sizeof(u16);     // 4 MB
  const size_t a2_bytes = (size_t)BATCH * A_DIM * sizeof(float);   // 512 KB
  const size_t sc_bytes = (size_t)MROWS * sizeof(float);           // 100 KB
  char* ws = (char*)d_ws;
  u16*   WT     = (u16*)ws;
  float* attn2p = (float*)(ws + wt_bytes);
  float* scores = (float*)(ws + wt_bytes + a2_bytes);

  // only scores needs zeroing (gemm epilogue accumulates atomically)
  hipMemsetAsync(scores, 0, sc_bytes, stream);

  wenc_cvt_kernel<<<dim3(F_DIM / 32, A_DIM / 32), 256, 0, stream>>>(W_enc, WT);
  attn2_kernel<<<dim3(A_DIM / 256, BATCH / 4), 256, 0, stream>>>(hidden, W_hid, b_hid, b_enc, attn2p);
  gemm_score<<<dim3(416), 512, 0, stream>>>(enc, WT, attn2p, W_full, scores);
  softmax_kernel<<<dim3(BATCH), 256, 0, stream>>>(scores, alpha_out);
  context_kernel<<<dim3(8, BATCH), 256, 0, stream>>>(enc, alpha_out, out);
}